// Round 3
// baseline (490.459 us; speedup 1.0000x reference)
//
#include <hip/hip_runtime.h>

// DCGRU cell, MI355X. Round 3:
//   cheb_gemm rewritten: fragment-ordered LDS subtiles (conflict-free stride-1
//   ds_read_b128), BK=64, double-buffered LDS with global_load_lds prefetch
//   issued before the compute phase (barrier drain overlapped by 32 MFMAs).
//   proj1/proj2: MFMA GEMM per (n-block,b); W packed bf16 K-contiguous; unroll 2.
//   d_out doubles as u-buffer (identical index layout (b*1024+n)*64+o).

typedef unsigned short u16;
typedef unsigned int u32;
typedef short s16x8 __attribute__((ext_vector_type(8)));
typedef float f32x4 __attribute__((ext_vector_type(4)));
typedef u16 u16x4 __attribute__((ext_vector_type(4)));

#define NN 1024
#define NB 64
#define NF 66
#define NCOLS 4224  // NF*NB
#define KPAD 352    // 330 padded to 11*32

__device__ __forceinline__ u16 f2bf(float f) {
  u32 u = __builtin_bit_cast(u32, f);
  u = (u + 0x7fffu + ((u >> 16) & 1u)) >> 16;  // RNE
  return (u16)u;
}
__device__ __forceinline__ float bf2f(u16 h) {
  u32 u = ((u32)h) << 16;
  return __builtin_bit_cast(float, u);
}

__device__ __forceinline__ void gload16(const void* g, void* l) {
  __builtin_amdgcn_global_load_lds(
      (const __attribute__((address_space(1))) u32*)g,
      (__attribute__((address_space(3))) u32*)l, 16, 0, 0);
}

// ---------------- pack kernels ----------------

__global__ __launch_bounds__(256) void pack_supports(
    const float* __restrict__ s0, const float* __restrict__ s1,
    u16* __restrict__ d0, u16* __restrict__ d1) {
  int i = (blockIdx.x * 256 + threadIdx.x) * 4;
  f32x4 a = *(const f32x4*)(s0 + i);
  f32x4 b = *(const f32x4*)(s1 + i);
  u16x4 oa, ob;
  oa.x = f2bf(a.x); oa.y = f2bf(a.y); oa.z = f2bf(a.z); oa.w = f2bf(a.w);
  ob.x = f2bf(b.x); ob.y = f2bf(b.y); ob.z = f2bf(b.z); ob.w = f2bf(b.w);
  *(u16x4*)(d0 + i) = oa;
  *(u16x4*)(d1 + i) = ob;
}

// Wt[o][kp] = W[f*5+m][o], kp = m*66+f, zero-padded kp in [330,352)
__global__ __launch_bounds__(64) void pack_w(
    const float* __restrict__ W, u16* __restrict__ Wt, int ldo) {
  int o = blockIdx.y;
  int kp = blockIdx.x * 64 + threadIdx.x;
  if (kp >= KPAD) return;
  float v = 0.f;
  if (kp < 330) {
    int m = kp / 66;
    int f = kp - m * 66;
    v = W[(f * 5 + m) * ldo + o];
  }
  Wt[(size_t)o * KPAD + kp] = f2bf(v);
}

// rows f=0,1 of X0^T and X0'^T: X0T[f*64+b][n] = inputs[b][2n+f]
__global__ __launch_bounds__(256) void pack_x0_inputs(
    const float* __restrict__ inp, u16* __restrict__ x0t, u16* __restrict__ x0pt) {
  int b = blockIdx.x, t = threadIdx.x;
  int n4 = t * 4;
  const float* src = inp + b * 2048 + n4 * 2;
  f32x4 a = *(const f32x4*)src;
  f32x4 c = *(const f32x4*)(src + 4);
  u16x4 r0, r1;
  r0.x = f2bf(a.x); r0.y = f2bf(a.z); r0.z = f2bf(c.x); r0.w = f2bf(c.z);  // f=0
  r1.x = f2bf(a.y); r1.y = f2bf(a.w); r1.z = f2bf(c.y); r1.w = f2bf(c.w);  // f=1
  size_t o0 = (size_t)(b)*NN + n4;
  size_t o1 = (size_t)(64 + b) * NN + n4;
  *(u16x4*)(x0t + o0) = r0;  *(u16x4*)(x0t + o1) = r1;
  *(u16x4*)(x0pt + o0) = r0; *(u16x4*)(x0pt + o1) = r1;
}

// rows f>=2 of X0^T: X0T[(2+u)*64+b][n] = hx[b][n*64+u]  (64x64 LDS transpose tiles)
__global__ __launch_bounds__(256) void pack_x0_hx(
    const float* __restrict__ hx, u16* __restrict__ x0t) {
  __shared__ float tile[64][65];
  int n0 = blockIdx.x * 64, b = blockIdx.y, t = threadIdx.x;
  int u4 = (t & 15) * 4, r0 = t >> 4;
#pragma unroll
  for (int p = 0; p < 4; p++) {
    int row = p * 16 + r0;
    f32x4 v = *(const f32x4*)(hx + ((size_t)b << 16) + (size_t)(n0 + row) * 64 + u4);
    tile[row][u4] = v.x; tile[row][u4 + 1] = v.y;
    tile[row][u4 + 2] = v.z; tile[row][u4 + 3] = v.w;
  }
  __syncthreads();
  int n4 = (t & 15) * 4, uu0 = t >> 4;
#pragma unroll
  for (int p = 0; p < 4; p++) {
    int u = p * 16 + uu0;
    u16x4 o;
    o.x = f2bf(tile[n4][u]);     o.y = f2bf(tile[n4 + 1][u]);
    o.z = f2bf(tile[n4 + 2][u]); o.w = f2bf(tile[n4 + 3][u]);
    *(u16x4*)&x0t[(size_t)((2 + u) * 64 + b) * NN + n0 + n4] = o;
  }
}

// ---------------- Chebyshev GEMM ----------------
// C[node][col] = S_z[node][:] . XT_z[col][:], write Xo_z[col][node] (bf16),
// optional fused epilogue: 2*C - Xprev.
// LDS: fragment-ordered subtiles: [kc][s][lane*8], subtile = 16 rows x 32 k,
// lane L holds row L&15, k-offset (L>>4)*8 (== MFMA A/B operand layout).
__global__ __launch_bounds__(256) void cheb_gemm(
    const u16* __restrict__ S0, const u16* __restrict__ S1,
    const u16* __restrict__ Xi0, const u16* __restrict__ Xi1,
    u16* __restrict__ Xo0, u16* __restrict__ Xo1,
    const u16* __restrict__ Xprev, int use_prev) {
  __shared__ u16 As[2][8192];  // [buf][kc*4096 + s*512 + lane*8]
  __shared__ u16 Bs[2][8192];
  const int t = threadIdx.x;
  const int lane = t & 63;
  const int w = t >> 6;
  const int n0 = blockIdx.x * 128;  // col tile (XT row)
  const int m0 = blockIdx.y * 128;  // node tile
  const u16* S = blockIdx.z ? S1 : S0;
  const u16* Xi = blockIdx.z ? Xi1 : Xi0;
  u16* Xo = blockIdx.z ? Xo1 : Xo0;

  const int srow = lane & 15;
  const int skof = (lane >> 4) * 8;

  // global base pointers for this wave's staged subtiles (s = 2w, 2w+1)
  const u16* gA[2];
  const u16* gB[2];
#pragma unroll
  for (int si = 0; si < 2; si++) {
    int s = 2 * w + si;
    gA[si] = S + (size_t)(m0 + s * 16 + srow) * NN + skof;
    gB[si] = Xi + (size_t)(n0 + s * 16 + srow) * NN + skof;
  }

  f32x4 acc[4][4];
#pragma unroll
  for (int i = 0; i < 4; i++)
#pragma unroll
    for (int j = 0; j < 4; j++) acc[i][j] = f32x4{0.f, 0.f, 0.f, 0.f};

  const int wA = (w >> 1) * 4;  // A subtile base for this wave's fragments
  const int wB = (w & 1) * 4;

#define STAGE(buf, k0)                                                     \
  {                                                                        \
    _Pragma("unroll") for (int si = 0; si < 2; si++) {                     \
      int s = 2 * w + si;                                                  \
      _Pragma("unroll") for (int kc = 0; kc < 2; kc++) {                   \
        gload16(gA[si] + (k0) + kc * 32, &As[buf][kc * 4096 + s * 512]);   \
        gload16(gB[si] + (k0) + kc * 32, &Bs[buf][kc * 4096 + s * 512]);   \
      }                                                                    \
    }                                                                      \
  }

#define COMPUTE(buf)                                                        \
  {                                                                         \
    _Pragma("unroll") for (int kc = 0; kc < 2; kc++) {                      \
      s16x8 af[4], bfr[4];                                                  \
      _Pragma("unroll") for (int i = 0; i < 4; i++)                         \
          af[i] = *(const s16x8*)&As[buf][kc * 4096 + (wA + i) * 512 + lane * 8]; \
      _Pragma("unroll") for (int j = 0; j < 4; j++)                         \
          bfr[j] = *(const s16x8*)&Bs[buf][kc * 4096 + (wB + j) * 512 + lane * 8]; \
      _Pragma("unroll") for (int i = 0; i < 4; i++)                         \
          _Pragma("unroll") for (int j = 0; j < 4; j++)                     \
              acc[i][j] = __builtin_amdgcn_mfma_f32_16x16x32_bf16(          \
                  af[i], bfr[j], acc[i][j], 0, 0, 0);                       \
    }                                                                       \
  }

  STAGE(0, 0);
  int buf = 0;
  for (int k0 = 64; k0 < 1024; k0 += 64) {
    __syncthreads();          // staging of `buf` complete; prev reads done
    STAGE(buf ^ 1, k0);       // prefetch next tile (in flight during compute)
    COMPUTE(buf);
    buf ^= 1;
  }
  __syncthreads();
  COMPUTE(buf);
#undef STAGE
#undef COMPUTE

  // C/D layout: col = lane&15, row = (lane>>4)*4 + reg
  const int wm = (w >> 1) * 64;
  const int wn = (w & 1) * 64;
  const int fr = lane & 15;
  const int nr0 = (lane >> 4) << 2;
#pragma unroll
  for (int i = 0; i < 4; i++) {
    const int node = m0 + wm + i * 16 + nr0;
#pragma unroll
    for (int j = 0; j < 4; j++) {
      const int colg = n0 + wn + j * 16 + fr;
      size_t off = (size_t)colg * NN + node;
      f32x4 c = acc[i][j];
      if (use_prev) {
        u16x4 p = *(const u16x4*)&Xprev[off];
        c.x = 2.f * c.x - bf2f(p.x);
        c.y = 2.f * c.y - bf2f(p.y);
        c.z = 2.f * c.z - bf2f(p.z);
        c.w = 2.f * c.w - bf2f(p.w);
      }
      u16x4 o;
      o.x = f2bf(c.x); o.y = f2bf(c.y); o.z = f2bf(c.z); o.w = f2bf(c.w);
      *(u16x4*)&Xo[off] = o;
    }
  }
}

// ---------------- projections (MFMA) ----------------

// stage activation slice into LDS A[kp][n], row stride 66, kp = mm*66+f
__device__ __forceinline__ void stage_x(u16* A, const u16* __restrict__ X, int mm,
                                        int b, int n0, int t) {
  for (int idx = t; idx < 66 * 32; idx += 256) {
    int f = idx >> 5, pos = (idx & 31) * 2;
    *(u32*)&A[(mm * 66 + f) * 66 + pos] =
        *(const u32*)(X + (size_t)(f * 64 + b) * NN + n0 + pos);
  }
}

__device__ __forceinline__ void zero_pad_rows(u16* A, int t) {
  u32* A32 = (u32*)A;
  for (int idx = t; idx < (KPAD - 330) * 33; idx += 256) A32[330 * 33 + idx] = 0;
}

// gconv1 projection: [64n x 330] @ Wt1^T -> 128 outs; sigmoid; r*hx -> X0'^T; u -> uout.
__global__ __launch_bounds__(256) void proj1(
    const u16* __restrict__ X0, const u16* __restrict__ X1, const u16* __restrict__ X2,
    const u16* __restrict__ X3, const u16* __restrict__ X4,
    const u16* __restrict__ Wt, const float* __restrict__ bias,
    const float* __restrict__ hx, u16* __restrict__ X0p, float* __restrict__ uout) {
  __shared__ u16 A[KPAD * 66];
  const int t = threadIdx.x;
  const int n0 = blockIdx.x * 64;
  const int b = blockIdx.y;
  stage_x(A, X0, 0, b, n0, t);
  stage_x(A, X1, 1, b, n0, t);
  stage_x(A, X2, 2, b, n0, t);
  stage_x(A, X3, 3, b, n0, t);
  stage_x(A, X4, 4, b, n0, t);
  zero_pad_rows(A, t);
  __syncthreads();

  const int lane = t & 63;
  const int w = t >> 6;
  const int fr = lane & 15;
  const int ko8 = (lane >> 4) * 8;

  f32x4 acc[8];
#pragma unroll
  for (int j = 0; j < 8; j++) acc[j] = f32x4{0.f, 0.f, 0.f, 0.f};

#pragma unroll 2
  for (int kc = 0; kc < KPAD; kc += 32) {
    s16x8 af;
#pragma unroll
    for (int j = 0; j < 8; j++)
      af[j] = (short)A[(kc + ko8 + j) * 66 + w * 16 + fr];
#pragma unroll
    for (int j = 0; j < 8; j++) {
      s16x8 bf = *(const s16x8*)&Wt[(size_t)(j * 16 + fr) * KPAD + kc + ko8];
      acc[j] = __builtin_amdgcn_mfma_f32_16x16x32_bf16(af, bf, acc[j], 0, 0, 0);
    }
  }

  // D layout: col(o within sub) = lane&15, row(n within sub) = (lane>>4)*4 + reg
  const int nl0 = (lane >> 4) * 4;
  const int n = n0 + w * 16 + nl0;  // + reg
#pragma unroll
  for (int j = 0; j < 8; j++) {
    const int o = j * 16 + fr;
    const float bs = bias[o];
    f32x4 v;
    v.x = 1.f / (1.f + __expf(-(acc[j].x + bs)));
    v.y = 1.f / (1.f + __expf(-(acc[j].y + bs)));
    v.z = 1.f / (1.f + __expf(-(acc[j].z + bs)));
    v.w = 1.f / (1.f + __expf(-(acc[j].w + bs)));
    if (o < 64) {  // r-part -> X0'^T row (2+o)*64+b, times hx
      const float* hxp = hx + ((size_t)b << 16) + (size_t)n * 64 + o;
      u16x4 s;
      s.x = f2bf(v.x * hxp[0 * 64]);
      s.y = f2bf(v.y * hxp[1 * 64]);
      s.z = f2bf(v.z * hxp[2 * 64]);
      s.w = f2bf(v.w * hxp[3 * 64]);
      *(u16x4*)&X0p[(size_t)((2 + o) * 64 + b) * NN + n] = s;
    } else {  // u-part -> uout (d_out scratch)
      float* up = uout + (((size_t)b << 10) + n) * 64 + (o - 64);
      up[0 * 64] = v.x; up[1 * 64] = v.y; up[2 * 64] = v.z; up[3 * 64] = v.w;
    }
  }
}

// gconv2 projection: tanh + GRU blend. uin aliases out (same layout) - no restrict.
__global__ __launch_bounds__(256) void proj2(
    const u16* __restrict__ X0, const u16* __restrict__ X1, const u16* __restrict__ X2,
    const u16* __restrict__ X3, const u16* __restrict__ X4,
    const u16* __restrict__ Wt, const float* __restrict__ bias,
    const float* __restrict__ hx, const float* uin, float* out) {
  __shared__ u16 A[KPAD * 66];
  const int t = threadIdx.x;
  const int n0 = blockIdx.x * 64;
  const int b = blockIdx.y;
  stage_x(A, X0, 0, b, n0, t);
  stage_x(A, X1, 1, b, n0, t);
  stage_x(A, X2, 2, b, n0, t);
  stage_x(A, X3, 3, b, n0, t);
  stage_x(A, X4, 4, b, n0, t);
  zero_pad_rows(A, t);
  __syncthreads();

  const int lane = t & 63;
  const int w = t >> 6;
  const int fr = lane & 15;
  const int ko8 = (lane >> 4) * 8;

  f32x4 acc[4];
#pragma unroll
  for (int j = 0; j < 4; j++) acc[j] = f32x4{0.f, 0.f, 0.f, 0.f};

#pragma unroll 2
  for (int kc = 0; kc < KPAD; kc += 32) {
    s16x8 af;
#pragma unroll
    for (int j = 0; j < 8; j++)
      af[j] = (short)A[(kc + ko8 + j) * 66 + w * 16 + fr];
#pragma unroll
    for (int j = 0; j < 4; j++) {
      s16x8 bf = *(const s16x8*)&Wt[(size_t)(j * 16 + fr) * KPAD + kc + ko8];
      acc[j] = __builtin_amdgcn_mfma_f32_16x16x32_bf16(af, bf, acc[j], 0, 0, 0);
    }
  }

  const int nl0 = (lane >> 4) * 4;
  const int n = n0 + w * 16 + nl0;  // + reg
#pragma unroll
  for (int j = 0; j < 4; j++) {
    const int o = j * 16 + fr;
    const float bs = bias[o];
    const size_t base = (((size_t)b << 10) + n) * 64 + o;  // + reg*64
    float c0 = tanhf(acc[j].x + bs);
    float c1 = tanhf(acc[j].y + bs);
    float c2 = tanhf(acc[j].z + bs);
    float c3 = tanhf(acc[j].w + bs);
    float u0 = uin[base + 0 * 64], u1 = uin[base + 1 * 64];
    float u2 = uin[base + 2 * 64], u3 = uin[base + 3 * 64];
    float h0 = hx[base + 0 * 64], h1 = hx[base + 1 * 64];
    float h2 = hx[base + 2 * 64], h3 = hx[base + 3 * 64];
    out[base + 0 * 64] = u0 * h0 + (1.f - u0) * c0;
    out[base + 1 * 64] = u1 * h1 + (1.f - u1) * c1;
    out[base + 2 * 64] = u2 * h2 + (1.f - u2) * c2;
    out[base + 3 * 64] = u3 * h3 + (1.f - u3) * c3;
  }
}

// ---------------- launch ----------------

extern "C" void kernel_launch(void* const* d_in, const int* in_sizes, int n_in,
                              void* d_out, int out_size, void* d_ws, size_t ws_size,
                              hipStream_t stream) {
  (void)in_sizes; (void)n_in; (void)out_size; (void)ws_size;
  const float* inp = (const float*)d_in[0];
  const float* hx  = (const float*)d_in[1];
  const float* s0  = (const float*)d_in[2];
  const float* s1  = (const float*)d_in[3];
  const float* Wo  = (const float*)d_in[4];
  const float* bo  = (const float*)d_in[5];
  const float* Wu  = (const float*)d_in[6];
  const float* bu  = (const float*)d_in[7];
  float* out = (float*)d_out;

  char* p = (char*)d_ws;
  u16* Sb0 = (u16*)p; p += (size_t)NN * NN * 2;
  u16* Sb1 = (u16*)p; p += (size_t)NN * NN * 2;
  const size_t xbytes = (size_t)NCOLS * NN * 2;
  u16* X0T = (u16*)p; p += xbytes;
  u16* X1T = (u16*)p; p += xbytes;
  u16* X2T = (u16*)p; p += xbytes;
  u16* X3T = (u16*)p; p += xbytes;
  u16* X4T = (u16*)p; p += xbytes;
  u16* X0P = (u16*)p; p += xbytes;
  u16* Wt1 = (u16*)p; p += (size_t)128 * KPAD * 2;
  u16* Wt2 = (u16*)p; p += (size_t)64 * KPAD * 2;
  // total ws use: 4 MB + 6*8.25 MB + ~132 KB

  pack_supports<<<dim3(1024), dim3(256), 0, stream>>>(s0, s1, Sb0, Sb1);
  pack_w<<<dim3(6, 128), dim3(64), 0, stream>>>(Wo, Wt1, 128);
  pack_w<<<dim3(6, 64), dim3(64), 0, stream>>>(Wu, Wt2, 64);
  pack_x0_inputs<<<dim3(64), dim3(256), 0, stream>>>(inp, X0T, X0P);
  pack_x0_hx<<<dim3(16, 64), dim3(256), 0, stream>>>(hx, X0T);
  // gconv1 Chebyshev: X1=S0 X0, X3=S1 X0 ; X2=2 S0 X1 - X0, X4=2 S1 X3 - X0
  cheb_gemm<<<dim3(33, 8, 2), dim3(256), 0, stream>>>(Sb0, Sb1, X0T, X0T, X1T, X3T,
                                                      (const u16*)nullptr, 0);
  cheb_gemm<<<dim3(33, 8, 2), dim3(256), 0, stream>>>(Sb0, Sb1, X1T, X3T, X2T, X4T, X0T, 1);
  proj1<<<dim3(16, 64), dim3(256), 0, stream>>>(X0T, X1T, X2T, X3T, X4T, Wt1, bo, hx, X0P, out);
  // gconv2 Chebyshev on X0' (reuse X1..X4 buffers)
  cheb_gemm<<<dim3(33, 8, 2), dim3(256), 0, stream>>>(Sb0, Sb1, X0P, X0P, X1T, X3T,
                                                      (const u16*)nullptr, 0);
  cheb_gemm<<<dim3(33, 8, 2), dim3(256), 0, stream>>>(Sb0, Sb1, X1T, X3T, X2T, X4T, X0P, 1);
  proj2<<<dim3(16, 64), dim3(256), 0, stream>>>(X0P, X1T, X2T, X3T, X4T, Wt2, bu, hx, out, out);
}

// Round 5
// 475.458 us; speedup vs baseline: 1.0316x; 1.0316x over previous
//
#include <hip/hip_runtime.h>

// DCGRU cell, MI355X. Round 5 (= R4 design + pad-overflow fix):
//   cheb_gemm: 64(col)x128(node) tile, BK=32, single-buffered 2-barrier K-loop
//   (R3 lesson: explicit dbuf loses -> go TLP). Fragment-ordered LDS subtiles
//   (0 bank conflicts, verified R3). Grid 72x8x2, XCD swizzle xt=(bx&7)*9+(bx>>3).
//   proj1/proj2: A staged [n][kp] stride 360 -> A-frag = 1 ds_read_b128;
//   B-frag global loads batched before MFMAs.
//   R4 BUG FIX: zero_pad_rows padded 32 entries (kp 330..361) overflowing the
//   360-wide row into the next row's kp=0,1 (racing stage_x, killing the x0
//   term). Now pads exactly kp 330..351 (MFMA reads stop at 351).
//   d_out doubles as u-buffer (identical index layout (b*1024+n)*64+o).

typedef unsigned short u16;
typedef unsigned int u32;
typedef short s16x8 __attribute__((ext_vector_type(8)));
typedef float f32x4 __attribute__((ext_vector_type(4)));
typedef u16 u16x4 __attribute__((ext_vector_type(4)));

#define NN 1024
#define NB 64
#define NF 66
#define NCOLS 4224  // NF*NB
#define KPAD 352    // 330 padded to 11*32 (Wt row length)
#define KSTR 360    // proj LDS A row stride (bank-spread: 180 dwords, 180%32=20)

__device__ __forceinline__ u16 f2bf(float f) {
  u32 u = __builtin_bit_cast(u32, f);
  u = (u + 0x7fffu + ((u >> 16) & 1u)) >> 16;  // RNE
  return (u16)u;
}
__device__ __forceinline__ float bf2f(u16 h) {
  u32 u = ((u32)h) << 16;
  return __builtin_bit_cast(float, u);
}

__device__ __forceinline__ void gload16(const void* g, void* l) {
  __builtin_amdgcn_global_load_lds(
      (const __attribute__((address_space(1))) u32*)g,
      (__attribute__((address_space(3))) u32*)l, 16, 0, 0);
}

// ---------------- pack kernels ----------------

__global__ __launch_bounds__(256) void pack_supports(
    const float* __restrict__ s0, const float* __restrict__ s1,
    u16* __restrict__ d0, u16* __restrict__ d1) {
  int i = (blockIdx.x * 256 + threadIdx.x) * 4;
  f32x4 a = *(const f32x4*)(s0 + i);
  f32x4 b = *(const f32x4*)(s1 + i);
  u16x4 oa, ob;
  oa.x = f2bf(a.x); oa.y = f2bf(a.y); oa.z = f2bf(a.z); oa.w = f2bf(a.w);
  ob.x = f2bf(b.x); ob.y = f2bf(b.y); ob.z = f2bf(b.z); ob.w = f2bf(b.w);
  *(u16x4*)(d0 + i) = oa;
  *(u16x4*)(d1 + i) = ob;
}

// Wt[o][kp] = W[f*5+m][o], kp = m*66+f, zero-padded kp in [330,352)
__global__ __launch_bounds__(64) void pack_w(
    const float* __restrict__ W, u16* __restrict__ Wt, int ldo) {
  int o = blockIdx.y;
  int kp = blockIdx.x * 64 + threadIdx.x;
  if (kp >= KPAD) return;
  float v = 0.f;
  if (kp < 330) {
    int m = kp / 66;
    int f = kp - m * 66;
    v = W[(f * 5 + m) * ldo + o];
  }
  Wt[(size_t)o * KPAD + kp] = f2bf(v);
}

// rows f=0,1 of X0^T and X0'^T: X0T[f*64+b][n] = inputs[b][2n+f]
__global__ __launch_bounds__(256) void pack_x0_inputs(
    const float* __restrict__ inp, u16* __restrict__ x0t, u16* __restrict__ x0pt) {
  int b = blockIdx.x, t = threadIdx.x;
  int n4 = t * 4;
  const float* src = inp + b * 2048 + n4 * 2;
  f32x4 a = *(const f32x4*)src;
  f32x4 c = *(const f32x4*)(src + 4);
  u16x4 r0, r1;
  r0.x = f2bf(a.x); r0.y = f2bf(a.z); r0.z = f2bf(c.x); r0.w = f2bf(c.z);  // f=0
  r1.x = f2bf(a.y); r1.y = f2bf(a.w); r1.z = f2bf(c.y); r1.w = f2bf(c.w);  // f=1
  size_t o0 = (size_t)(b)*NN + n4;
  size_t o1 = (size_t)(64 + b) * NN + n4;
  *(u16x4*)(x0t + o0) = r0;  *(u16x4*)(x0t + o1) = r1;
  *(u16x4*)(x0pt + o0) = r0; *(u16x4*)(x0pt + o1) = r1;
}

// rows f>=2 of X0^T: X0T[(2+u)*64+b][n] = hx[b][n*64+u]  (64x64 LDS transpose tiles)
__global__ __launch_bounds__(256) void pack_x0_hx(
    const float* __restrict__ hx, u16* __restrict__ x0t) {
  __shared__ float tile[64][65];
  int n0 = blockIdx.x * 64, b = blockIdx.y, t = threadIdx.x;
  int u4 = (t & 15) * 4, r0 = t >> 4;
#pragma unroll
  for (int p = 0; p < 4; p++) {
    int row = p * 16 + r0;
    f32x4 v = *(const f32x4*)(hx + ((size_t)b << 16) + (size_t)(n0 + row) * 64 + u4);
    tile[row][u4] = v.x; tile[row][u4 + 1] = v.y;
    tile[row][u4 + 2] = v.z; tile[row][u4 + 3] = v.w;
  }
  __syncthreads();
  int n4 = (t & 15) * 4, uu0 = t >> 4;
#pragma unroll
  for (int p = 0; p < 4; p++) {
    int u = p * 16 + uu0;
    u16x4 o;
    o.x = f2bf(tile[n4][u]);     o.y = f2bf(tile[n4 + 1][u]);
    o.z = f2bf(tile[n4 + 2][u]); o.w = f2bf(tile[n4 + 3][u]);
    *(u16x4*)&x0t[(size_t)((2 + u) * 64 + b) * NN + n0 + n4] = o;
  }
}

// ---------------- Chebyshev GEMM ----------------
// C[node][col] = S_z[node][:] . XT_z[col][:], write Xo_z[col][node] (bf16),
// optional fused epilogue: 2*C - Xprev.
// Tile 64 cols x 128 nodes, BK=32. LDS fragment-ordered subtiles:
// subtile s = 16 rows x 32 k at [s*512 + lane*8]; lane L holds row L&15,
// k-offset (L>>4)*8 (== MFMA A/B operand layout -> stride-1 ds_read_b128).
__global__ __launch_bounds__(256) void cheb_gemm(
    const u16* __restrict__ S0, const u16* __restrict__ S1,
    const u16* __restrict__ Xi0, const u16* __restrict__ Xi1,
    u16* __restrict__ Xo0, u16* __restrict__ Xo1,
    const u16* __restrict__ Xprev, int use_prev) {
  __shared__ u16 As[8 * 512];  // 128 nodes
  __shared__ u16 Bs[4 * 512];  // 64 cols
  const int t = threadIdx.x;
  const int lane = t & 63;
  const int w = t >> 6;
  // XCD swizzle: consecutive HW blocks (x%8) -> different XCDs; give each XCD
  // 9 contiguous col-tiles (x&7 selects the 9-tile group).
  const int xt = (blockIdx.x & 7) * 9 + (blockIdx.x >> 3);
  if (xt >= 66) return;
  const int n0 = xt * 64;          // col tile (XT row)
  const int m0 = blockIdx.y * 128; // node tile
  const u16* S = blockIdx.z ? S1 : S0;
  const u16* Xi = blockIdx.z ? Xi1 : Xi0;
  u16* Xo = blockIdx.z ? Xo1 : Xo0;

  const int srow = lane & 15;
  const int skof = (lane >> 4) * 8;
  // wave w stages A subtiles {2w,2w+1} and B subtile {w}
  const u16* gA0 = S + (size_t)(m0 + (2 * w) * 16 + srow) * NN + skof;
  const u16* gA1 = gA0 + (size_t)16 * NN;
  const u16* gB = Xi + (size_t)(n0 + w * 16 + srow) * NN + skof;
  u16* lA0 = &As[(2 * w) * 512];
  u16* lA1 = &As[(2 * w + 1) * 512];
  u16* lB = &Bs[w * 512];

  f32x4 acc[4][2];
#pragma unroll
  for (int i = 0; i < 4; i++)
#pragma unroll
    for (int j = 0; j < 2; j++) acc[i][j] = f32x4{0.f, 0.f, 0.f, 0.f};

  const int wmA = (w >> 1) * 4;  // wave covers 64 nodes (4 subtiles)
  const int wnB = (w & 1) * 2;   // and 32 cols (2 subtiles)

  for (int k0 = 0; k0 < 1024; k0 += 32) {
    __syncthreads();
    gload16(gA0 + k0, lA0);
    gload16(gA1 + k0, lA1);
    gload16(gB + k0, lB);
    __syncthreads();
    s16x8 af[4], bfr[2];
#pragma unroll
    for (int i = 0; i < 4; i++)
      af[i] = *(const s16x8*)&As[(wmA + i) * 512 + lane * 8];
#pragma unroll
    for (int j = 0; j < 2; j++)
      bfr[j] = *(const s16x8*)&Bs[(wnB + j) * 512 + lane * 8];
#pragma unroll
    for (int i = 0; i < 4; i++)
#pragma unroll
      for (int j = 0; j < 2; j++)
        acc[i][j] = __builtin_amdgcn_mfma_f32_16x16x32_bf16(af[i], bfr[j], acc[i][j], 0, 0, 0);
  }

  // C/D layout: col = lane&15, row = (lane>>4)*4 + reg
  const int fr = lane & 15;
  const int nr0 = (lane >> 4) * 4;
#pragma unroll
  for (int i = 0; i < 4; i++) {
    const int node = m0 + (w >> 1) * 64 + i * 16 + nr0;
#pragma unroll
    for (int j = 0; j < 2; j++) {
      const int colg = n0 + (w & 1) * 32 + j * 16 + fr;
      size_t off = (size_t)colg * NN + node;
      f32x4 c = acc[i][j];
      if (use_prev) {
        u16x4 p = *(const u16x4*)&Xprev[off];
        c.x = 2.f * c.x - bf2f(p.x);
        c.y = 2.f * c.y - bf2f(p.y);
        c.z = 2.f * c.z - bf2f(p.z);
        c.w = 2.f * c.w - bf2f(p.w);
      }
      u16x4 o;
      o.x = f2bf(c.x); o.y = f2bf(c.y); o.z = f2bf(c.z); o.w = f2bf(c.w);
      *(u16x4*)&Xo[off] = o;
    }
  }
}

// ---------------- projections (MFMA) ----------------

// stage activation slice into LDS A[n][kp], row stride KSTR, kp = mm*66+f.
// Pairs of consecutive f -> one u32 LDS write; 64-lane coalesced row reads.
__device__ __forceinline__ void stage_x(u32* A32, const u16* __restrict__ X, int mm,
                                        int b, int n0, int t) {
  for (int idx = t; idx < 33 * 64; idx += 256) {
    int p = idx >> 6, n = idx & 63, f = 2 * p;
    u32 v0 = X[(size_t)(f * 64 + b) * NN + n0 + n];
    u32 v1 = X[(size_t)((f + 1) * 64 + b) * NN + n0 + n];
    A32[n * (KSTR / 2) + mm * 33 + p] = v0 | (v1 << 16);
  }
}

// zero kp in [330, 352) ONLY (MFMA loop reads kp<=351; kp>=360 is next row!)
__device__ __forceinline__ void zero_pad_rows(u16* A, int t) {
  for (int idx = t; idx < 64 * 22; idx += 256) {
    int n = idx / 22, q = idx % 22;
    A[n * KSTR + 330 + q] = 0;
  }
}

// gconv1 projection: [64n x 330] @ Wt1^T -> 128 outs; sigmoid; r*hx -> X0'^T; u -> uout.
__global__ __launch_bounds__(256) void proj1(
    const u16* __restrict__ X0, const u16* __restrict__ X1, const u16* __restrict__ X2,
    const u16* __restrict__ X3, const u16* __restrict__ X4,
    const u16* __restrict__ Wt, const float* __restrict__ bias,
    const float* __restrict__ hx, u16* __restrict__ X0p, float* __restrict__ uout) {
  __shared__ u16 A[64 * KSTR + 16];
  const int t = threadIdx.x;
  const int n0 = blockIdx.x * 64;
  const int b = blockIdx.y;
  u32* A32 = (u32*)A;
  stage_x(A32, X0, 0, b, n0, t);
  stage_x(A32, X1, 1, b, n0, t);
  stage_x(A32, X2, 2, b, n0, t);
  stage_x(A32, X3, 3, b, n0, t);
  stage_x(A32, X4, 4, b, n0, t);
  zero_pad_rows(A, t);
  __syncthreads();

  const int lane = t & 63;
  const int w = t >> 6;
  const int fr = lane & 15;
  const int ko8 = (lane >> 4) * 8;

  f32x4 acc[8];
#pragma unroll
  for (int j = 0; j < 8; j++) acc[j] = f32x4{0.f, 0.f, 0.f, 0.f};

#pragma unroll 2
  for (int kc = 0; kc < KPAD; kc += 32) {
    s16x8 af = *(const s16x8*)&A[(w * 16 + fr) * KSTR + kc + ko8];
    s16x8 bf[8];
#pragma unroll
    for (int j = 0; j < 8; j++)
      bf[j] = *(const s16x8*)&Wt[(size_t)(j * 16 + fr) * KPAD + kc + ko8];
#pragma unroll
    for (int j = 0; j < 8; j++)
      acc[j] = __builtin_amdgcn_mfma_f32_16x16x32_bf16(af, bf[j], acc[j], 0, 0, 0);
  }

  // D layout: col(o within sub) = lane&15, row(n within sub) = (lane>>4)*4 + reg
  const int nl0 = (lane >> 4) * 4;
  const int n = n0 + w * 16 + nl0;  // + reg
#pragma unroll
  for (int j = 0; j < 8; j++) {
    const int o = j * 16 + fr;
    const float bs = bias[o];
    f32x4 v;
    v.x = 1.f / (1.f + __expf(-(acc[j].x + bs)));
    v.y = 1.f / (1.f + __expf(-(acc[j].y + bs)));
    v.z = 1.f / (1.f + __expf(-(acc[j].z + bs)));
    v.w = 1.f / (1.f + __expf(-(acc[j].w + bs)));
    if (o < 64) {  // r-part -> X0'^T row (2+o)*64+b, times hx
      const float* hxp = hx + ((size_t)b << 16) + (size_t)n * 64 + o;
      u16x4 s;
      s.x = f2bf(v.x * hxp[0 * 64]);
      s.y = f2bf(v.y * hxp[1 * 64]);
      s.z = f2bf(v.z * hxp[2 * 64]);
      s.w = f2bf(v.w * hxp[3 * 64]);
      *(u16x4*)&X0p[(size_t)((2 + o) * 64 + b) * NN + n] = s;
    } else {  // u-part -> uout (d_out scratch)
      float* up = uout + (((size_t)b << 10) + n) * 64 + (o - 64);
      up[0 * 64] = v.x; up[1 * 64] = v.y; up[2 * 64] = v.z; up[3 * 64] = v.w;
    }
  }
}

// gconv2 projection: tanh + GRU blend. uin aliases out (same layout) - no restrict.
__global__ __launch_bounds__(256) void proj2(
    const u16* __restrict__ X0, const u16* __restrict__ X1, const u16* __restrict__ X2,
    const u16* __restrict__ X3, const u16* __restrict__ X4,
    const u16* __restrict__ Wt, const float* __restrict__ bias,
    const float* __restrict__ hx, const float* uin, float* out) {
  __shared__ u16 A[64 * KSTR + 16];
  const int t = threadIdx.x;
  const int n0 = blockIdx.x * 64;
  const int b = blockIdx.y;
  u32* A32 = (u32*)A;
  stage_x(A32, X0, 0, b, n0, t);
  stage_x(A32, X1, 1, b, n0, t);
  stage_x(A32, X2, 2, b, n0, t);
  stage_x(A32, X3, 3, b, n0, t);
  stage_x(A32, X4, 4, b, n0, t);
  zero_pad_rows(A, t);
  __syncthreads();

  const int lane = t & 63;
  const int w = t >> 6;
  const int fr = lane & 15;
  const int ko8 = (lane >> 4) * 8;

  f32x4 acc[4];
#pragma unroll
  for (int j = 0; j < 4; j++) acc[j] = f32x4{0.f, 0.f, 0.f, 0.f};

#pragma unroll 2
  for (int kc = 0; kc < KPAD; kc += 32) {
    s16x8 af = *(const s16x8*)&A[(w * 16 + fr) * KSTR + kc + ko8];
    s16x8 bf[4];
#pragma unroll
    for (int j = 0; j < 4; j++)
      bf[j] = *(const s16x8*)&Wt[(size_t)(j * 16 + fr) * KPAD + kc + ko8];
#pragma unroll
    for (int j = 0; j < 4; j++)
      acc[j] = __builtin_amdgcn_mfma_f32_16x16x32_bf16(af, bf[j], acc[j], 0, 0, 0);
  }

  const int nl0 = (lane >> 4) * 4;
  const int n = n0 + w * 16 + nl0;  // + reg
#pragma unroll
  for (int j = 0; j < 4; j++) {
    const int o = j * 16 + fr;
    const float bs = bias[o];
    const size_t base = (((size_t)b << 10) + n) * 64 + o;  // + reg*64
    float c0 = tanhf(acc[j].x + bs);
    float c1 = tanhf(acc[j].y + bs);
    float c2 = tanhf(acc[j].z + bs);
    float c3 = tanhf(acc[j].w + bs);
    float u0 = uin[base + 0 * 64], u1 = uin[base + 1 * 64];
    float u2 = uin[base + 2 * 64], u3 = uin[base + 3 * 64];
    float h0 = hx[base + 0 * 64], h1 = hx[base + 1 * 64];
    float h2 = hx[base + 2 * 64], h3 = hx[base + 3 * 64];
    out[base + 0 * 64] = u0 * h0 + (1.f - u0) * c0;
    out[base + 1 * 64] = u1 * h1 + (1.f - u1) * c1;
    out[base + 2 * 64] = u2 * h2 + (1.f - u2) * c2;
    out[base + 3 * 64] = u3 * h3 + (1.f - u3) * c3;
  }
}

// ---------------- launch ----------------

extern "C" void kernel_launch(void* const* d_in, const int* in_sizes, int n_in,
                              void* d_out, int out_size, void* d_ws, size_t ws_size,
                              hipStream_t stream) {
  (void)in_sizes; (void)n_in; (void)out_size; (void)ws_size;
  const float* inp = (const float*)d_in[0];
  const float* hx  = (const float*)d_in[1];
  const float* s0  = (const float*)d_in[2];
  const float* s1  = (const float*)d_in[3];
  const float* Wo  = (const float*)d_in[4];
  const float* bo  = (const float*)d_in[5];
  const float* Wu  = (const float*)d_in[6];
  const float* bu  = (const float*)d_in[7];
  float* out = (float*)d_out;

  char* p = (char*)d_ws;
  u16* Sb0 = (u16*)p; p += (size_t)NN * NN * 2;
  u16* Sb1 = (u16*)p; p += (size_t)NN * NN * 2;
  const size_t xbytes = (size_t)NCOLS * NN * 2;
  u16* X0T = (u16*)p; p += xbytes;
  u16* X1T = (u16*)p; p += xbytes;
  u16* X2T = (u16*)p; p += xbytes;
  u16* X3T = (u16*)p; p += xbytes;
  u16* X4T = (u16*)p; p += xbytes;
  u16* X0P = (u16*)p; p += xbytes;
  u16* Wt1 = (u16*)p; p += (size_t)128 * KPAD * 2;
  u16* Wt2 = (u16*)p; p += (size_t)64 * KPAD * 2;
  // total ws use: 4 MB + 6*8.25 MB + ~132 KB

  pack_supports<<<dim3(1024), dim3(256), 0, stream>>>(s0, s1, Sb0, Sb1);
  pack_w<<<dim3(6, 128), dim3(64), 0, stream>>>(Wo, Wt1, 128);
  pack_w<<<dim3(6, 64), dim3(64), 0, stream>>>(Wu, Wt2, 64);
  pack_x0_inputs<<<dim3(64), dim3(256), 0, stream>>>(inp, X0T, X0P);
  pack_x0_hx<<<dim3(16, 64), dim3(256), 0, stream>>>(hx, X0T);
  // gconv1 Chebyshev: X1=S0 X0, X3=S1 X0 ; X2=2 S0 X1 - X0, X4=2 S1 X3 - X0
  cheb_gemm<<<dim3(72, 8, 2), dim3(256), 0, stream>>>(Sb0, Sb1, X0T, X0T, X1T, X3T,
                                                      (const u16*)nullptr, 0);
  cheb_gemm<<<dim3(72, 8, 2), dim3(256), 0, stream>>>(Sb0, Sb1, X1T, X3T, X2T, X4T, X0T, 1);
  proj1<<<dim3(16, 64), dim3(256), 0, stream>>>(X0T, X1T, X2T, X3T, X4T, Wt1, bo, hx, X0P, out);
  // gconv2 Chebyshev on X0' (reuse X1..X4 buffers)
  cheb_gemm<<<dim3(72, 8, 2), dim3(256), 0, stream>>>(Sb0, Sb1, X0P, X0P, X1T, X3T,
                                                      (const u16*)nullptr, 0);
  cheb_gemm<<<dim3(72, 8, 2), dim3(256), 0, stream>>>(Sb0, Sb1, X1T, X3T, X2T, X4T, X0P, 1);
  proj2<<<dim3(16, 64), dim3(256), 0, stream>>>(X0P, X1T, X2T, X3T, X4T, Wt2, bu, hx, out, out);
}

// Round 6
// 454.997 us; speedup vs baseline: 1.0779x; 1.0450x over previous
//
#include <hip/hip_runtime.h>

// DCGRU cell, MI355X. Round 6:
//   cheb_gemm K-loop restructured: register-skid pipeline. global_load_dwordx4
//   -> VGPR skid (distance 2) -> ds_write_b128 -> raw s_barrier (asm, lgkm-only
//   wait). No global_load_lds => no vmcnt(0) drain at barriers; compiler emits
//   precise vmcnt(N) before the ds_write consuming the skid regs (~2 iters
//   after issue => ~600-1000 cyc latency coverage). 64(col)x128(node) tile,
//   BK=32, fragment-ordered LDS subtiles (0 conflicts), XCD swizzle
//   xt=(bx&7)*9+(bx>>3) (FETCH 91->34 MB, verified R5).
//   proj1/proj2: A staged [n][kp] stride 360, 1 ds_read_b128 A-frag, batched
//   B-frag global loads (R5, verified).
//   d_out doubles as u-buffer (identical index layout (b*1024+n)*64+o).

typedef unsigned short u16;
typedef unsigned int u32;
typedef short s16x8 __attribute__((ext_vector_type(8)));
typedef float f32x4 __attribute__((ext_vector_type(4)));
typedef u16 u16x4 __attribute__((ext_vector_type(4)));

#define NN 1024
#define NB 64
#define NF 66
#define NCOLS 4224  // NF*NB
#define KPAD 352    // 330 padded to 11*32 (Wt row length)
#define KSTR 360    // proj LDS A row stride

// barrier without vmcnt drain: own LDS ops complete, then s_barrier.
// memory clobber pins LDS/global op issue order across it.
#define BAR() __asm__ volatile("s_waitcnt lgkmcnt(0)\n\ts_barrier" ::: "memory")

__device__ __forceinline__ u16 f2bf(float f) {
  u32 u = __builtin_bit_cast(u32, f);
  u = (u + 0x7fffu + ((u >> 16) & 1u)) >> 16;  // RNE
  return (u16)u;
}
__device__ __forceinline__ float bf2f(u16 h) {
  u32 u = ((u32)h) << 16;
  return __builtin_bit_cast(float, u);
}

// ---------------- pack kernels ----------------

__global__ __launch_bounds__(256) void pack_supports(
    const float* __restrict__ s0, const float* __restrict__ s1,
    u16* __restrict__ d0, u16* __restrict__ d1) {
  int i = (blockIdx.x * 256 + threadIdx.x) * 4;
  f32x4 a = *(const f32x4*)(s0 + i);
  f32x4 b = *(const f32x4*)(s1 + i);
  u16x4 oa, ob;
  oa.x = f2bf(a.x); oa.y = f2bf(a.y); oa.z = f2bf(a.z); oa.w = f2bf(a.w);
  ob.x = f2bf(b.x); ob.y = f2bf(b.y); ob.z = f2bf(b.z); ob.w = f2bf(b.w);
  *(u16x4*)(d0 + i) = oa;
  *(u16x4*)(d1 + i) = ob;
}

// Wt[o][kp] = W[f*5+m][o], kp = m*66+f, zero-padded kp in [330,352)
__global__ __launch_bounds__(64) void pack_w(
    const float* __restrict__ W, u16* __restrict__ Wt, int ldo) {
  int o = blockIdx.y;
  int kp = blockIdx.x * 64 + threadIdx.x;
  if (kp >= KPAD) return;
  float v = 0.f;
  if (kp < 330) {
    int m = kp / 66;
    int f = kp - m * 66;
    v = W[(f * 5 + m) * ldo + o];
  }
  Wt[(size_t)o * KPAD + kp] = f2bf(v);
}

// rows f=0,1 of X0^T and X0'^T: X0T[f*64+b][n] = inputs[b][2n+f]
__global__ __launch_bounds__(256) void pack_x0_inputs(
    const float* __restrict__ inp, u16* __restrict__ x0t, u16* __restrict__ x0pt) {
  int b = blockIdx.x, t = threadIdx.x;
  int n4 = t * 4;
  const float* src = inp + b * 2048 + n4 * 2;
  f32x4 a = *(const f32x4*)src;
  f32x4 c = *(const f32x4*)(src + 4);
  u16x4 r0, r1;
  r0.x = f2bf(a.x); r0.y = f2bf(a.z); r0.z = f2bf(c.x); r0.w = f2bf(c.z);  // f=0
  r1.x = f2bf(a.y); r1.y = f2bf(a.w); r1.z = f2bf(c.y); r1.w = f2bf(c.w);  // f=1
  size_t o0 = (size_t)(b)*NN + n4;
  size_t o1 = (size_t)(64 + b) * NN + n4;
  *(u16x4*)(x0t + o0) = r0;  *(u16x4*)(x0t + o1) = r1;
  *(u16x4*)(x0pt + o0) = r0; *(u16x4*)(x0pt + o1) = r1;
}

// rows f>=2 of X0^T: X0T[(2+u)*64+b][n] = hx[b][n*64+u]  (64x64 LDS transpose tiles)
__global__ __launch_bounds__(256) void pack_x0_hx(
    const float* __restrict__ hx, u16* __restrict__ x0t) {
  __shared__ float tile[64][65];
  int n0 = blockIdx.x * 64, b = blockIdx.y, t = threadIdx.x;
  int u4 = (t & 15) * 4, r0 = t >> 4;
#pragma unroll
  for (int p = 0; p < 4; p++) {
    int row = p * 16 + r0;
    f32x4 v = *(const f32x4*)(hx + ((size_t)b << 16) + (size_t)(n0 + row) * 64 + u4);
    tile[row][u4] = v.x; tile[row][u4 + 1] = v.y;
    tile[row][u4 + 2] = v.z; tile[row][u4 + 3] = v.w;
  }
  __syncthreads();
  int n4 = (t & 15) * 4, uu0 = t >> 4;
#pragma unroll
  for (int p = 0; p < 4; p++) {
    int u = p * 16 + uu0;
    u16x4 o;
    o.x = f2bf(tile[n4][u]);     o.y = f2bf(tile[n4 + 1][u]);
    o.z = f2bf(tile[n4 + 2][u]); o.w = f2bf(tile[n4 + 3][u]);
    *(u16x4*)&x0t[(size_t)((2 + u) * 64 + b) * NN + n0 + n4] = o;
  }
}

// ---------------- Chebyshev GEMM ----------------
// C[node][col] = S_z[node][:] . XT_z[col][:], write Xo_z[col][node] (bf16),
// optional fused epilogue: 2*C - Xprev.
// Tile 64 cols x 128 nodes, BK=32. LDS fragment-ordered subtiles:
// subtile s = 16 rows x 32 k at [s*512 + lane*8]; lane L holds row L&15,
// k-offset (L>>4)*8 (== MFMA A/B operand layout -> stride-1 ds_read_b128).
// K-loop: VGPR skid distance 2, ds_write_b128, raw barriers (no vmcnt drain).
__global__ __launch_bounds__(256) void cheb_gemm(
    const u16* __restrict__ S0, const u16* __restrict__ S1,
    const u16* __restrict__ Xi0, const u16* __restrict__ Xi1,
    u16* __restrict__ Xo0, u16* __restrict__ Xo1,
    const u16* __restrict__ Xprev, int use_prev) {
  __shared__ u16 As[8 * 512];  // 128 nodes
  __shared__ u16 Bs[4 * 512];  // 64 cols
  const int t = threadIdx.x;
  const int lane = t & 63;
  const int w = t >> 6;
  // XCD swizzle: consecutive HW blocks (x%8) -> different XCDs; each XCD gets
  // 9 contiguous col-tiles.
  const int xt = (blockIdx.x & 7) * 9 + (blockIdx.x >> 3);
  if (xt >= 66) return;
  const int n0 = xt * 64;          // col tile (XT row)
  const int m0 = blockIdx.y * 128; // node tile
  const u16* S = blockIdx.z ? S1 : S0;
  const u16* Xi = blockIdx.z ? Xi1 : Xi0;
  u16* Xo = blockIdx.z ? Xo1 : Xo0;

  const int srow = lane & 15;
  const int skof = (lane >> 4) * 8;
  // wave w stages A subtiles {2w,2w+1} and B subtile {w}
  const u16* gA0 = S + (size_t)(m0 + (2 * w) * 16 + srow) * NN + skof;
  const u16* gA1 = gA0 + (size_t)16 * NN;
  const u16* gB = Xi + (size_t)(n0 + w * 16 + srow) * NN + skof;
  u16* lA0 = &As[(2 * w) * 512 + lane * 8];
  u16* lA1 = &As[(2 * w + 1) * 512 + lane * 8];
  u16* lB = &Bs[w * 512 + lane * 8];

  f32x4 acc[4][2];
#pragma unroll
  for (int i = 0; i < 4; i++)
#pragma unroll
    for (int j = 0; j < 2; j++) acc[i][j] = f32x4{0.f, 0.f, 0.f, 0.f};

  const int wmA = (w >> 1) * 4;  // wave's 64 nodes (4 subtiles)
  const int wnB = (w & 1) * 2;   // wave's 32 cols (2 subtiles)

  // register skid, distance 2
  s16x8 rA0[2], rA1[2], rB[2];
  rA0[0] = *(const s16x8*)(gA0 + 0);
  rA1[0] = *(const s16x8*)(gA1 + 0);
  rB[0]  = *(const s16x8*)(gB + 0);
  rA0[1] = *(const s16x8*)(gA0 + 32);
  rA1[1] = *(const s16x8*)(gA1 + 32);
  rB[1]  = *(const s16x8*)(gB + 32);

#pragma unroll 2
  for (int k0 = 0; k0 < 1024; k0 += 32) {
    const int s = (k0 >> 5) & 1;
    // commit skid slot s (tile k0) to LDS; compiler inserts precise vmcnt(N)
    *(s16x8*)lA0 = rA0[s];
    *(s16x8*)lA1 = rA1[s];
    *(s16x8*)lB  = rB[s];
    BAR();  // writes visible to all waves; loads for k0+32.. still in flight
    // refill slot s with tile k0+64 (wrap keeps it branch-free; extra loads hit L2)
    const int kn = (k0 + 64) & 1023;
    rA0[s] = *(const s16x8*)(gA0 + kn);
    rA1[s] = *(const s16x8*)(gA1 + kn);
    rB[s]  = *(const s16x8*)(gB + kn);
    s16x8 af[4], bfr[2];
#pragma unroll
    for (int i = 0; i < 4; i++)
      af[i] = *(const s16x8*)&As[(wmA + i) * 512 + lane * 8];
#pragma unroll
    for (int j = 0; j < 2; j++)
      bfr[j] = *(const s16x8*)&Bs[(wnB + j) * 512 + lane * 8];
#pragma unroll
    for (int i = 0; i < 4; i++)
#pragma unroll
      for (int j = 0; j < 2; j++)
        acc[i][j] = __builtin_amdgcn_mfma_f32_16x16x32_bf16(af[i], bfr[j], acc[i][j], 0, 0, 0);
    BAR();  // all reads of this tile done before next iter's ds_write
  }

  // C/D layout: col = lane&15, row = (lane>>4)*4 + reg
  const int fr = lane & 15;
  const int nr0 = (lane >> 4) * 4;
#pragma unroll
  for (int i = 0; i < 4; i++) {
    const int node = m0 + (w >> 1) * 64 + i * 16 + nr0;
#pragma unroll
    for (int j = 0; j < 2; j++) {
      const int colg = n0 + (w & 1) * 32 + j * 16 + fr;
      size_t off = (size_t)colg * NN + node;
      f32x4 c = acc[i][j];
      if (use_prev) {
        u16x4 p = *(const u16x4*)&Xprev[off];
        c.x = 2.f * c.x - bf2f(p.x);
        c.y = 2.f * c.y - bf2f(p.y);
        c.z = 2.f * c.z - bf2f(p.z);
        c.w = 2.f * c.w - bf2f(p.w);
      }
      u16x4 o;
      o.x = f2bf(c.x); o.y = f2bf(c.y); o.z = f2bf(c.z); o.w = f2bf(c.w);
      *(u16x4*)&Xo[off] = o;
    }
  }
}

// ---------------- projections (MFMA) ----------------

// stage activation slice into LDS A[n][kp], row stride KSTR, kp = mm*66+f.
__device__ __forceinline__ void stage_x(u32* A32, const u16* __restrict__ X, int mm,
                                        int b, int n0, int t) {
  for (int idx = t; idx < 33 * 64; idx += 256) {
    int p = idx >> 6, n = idx & 63, f = 2 * p;
    u32 v0 = X[(size_t)(f * 64 + b) * NN + n0 + n];
    u32 v1 = X[(size_t)((f + 1) * 64 + b) * NN + n0 + n];
    A32[n * (KSTR / 2) + mm * 33 + p] = v0 | (v1 << 16);
  }
}

// zero kp in [330, 352) ONLY (MFMA loop reads kp<=351; kp>=360 is next row!)
__device__ __forceinline__ void zero_pad_rows(u16* A, int t) {
  for (int idx = t; idx < 64 * 22; idx += 256) {
    int n = idx / 22, q = idx % 22;
    A[n * KSTR + 330 + q] = 0;
  }
}

// gconv1 projection: [64n x 330] @ Wt1^T -> 128 outs; sigmoid; r*hx -> X0'^T; u -> uout.
__global__ __launch_bounds__(256) void proj1(
    const u16* __restrict__ X0, const u16* __restrict__ X1, const u16* __restrict__ X2,
    const u16* __restrict__ X3, const u16* __restrict__ X4,
    const u16* __restrict__ Wt, const float* __restrict__ bias,
    const float* __restrict__ hx, u16* __restrict__ X0p, float* __restrict__ uout) {
  __shared__ u16 A[64 * KSTR + 16];
  const int t = threadIdx.x;
  const int n0 = blockIdx.x * 64;
  const int b = blockIdx.y;
  u32* A32 = (u32*)A;
  stage_x(A32, X0, 0, b, n0, t);
  stage_x(A32, X1, 1, b, n0, t);
  stage_x(A32, X2, 2, b, n0, t);
  stage_x(A32, X3, 3, b, n0, t);
  stage_x(A32, X4, 4, b, n0, t);
  zero_pad_rows(A, t);
  __syncthreads();

  const int lane = t & 63;
  const int w = t >> 6;
  const int fr = lane & 15;
  const int ko8 = (lane >> 4) * 8;

  f32x4 acc[8];
#pragma unroll
  for (int j = 0; j < 8; j++) acc[j] = f32x4{0.f, 0.f, 0.f, 0.f};

#pragma unroll 2
  for (int kc = 0; kc < KPAD; kc += 32) {
    s16x8 af = *(const s16x8*)&A[(w * 16 + fr) * KSTR + kc + ko8];
    s16x8 bf[8];
#pragma unroll
    for (int j = 0; j < 8; j++)
      bf[j] = *(const s16x8*)&Wt[(size_t)(j * 16 + fr) * KPAD + kc + ko8];
#pragma unroll
    for (int j = 0; j < 8; j++)
      acc[j] = __builtin_amdgcn_mfma_f32_16x16x32_bf16(af, bf[j], acc[j], 0, 0, 0);
  }

  // D layout: col(o within sub) = lane&15, row(n within sub) = (lane>>4)*4 + reg
  const int nl0 = (lane >> 4) * 4;
  const int n = n0 + w * 16 + nl0;  // + reg
#pragma unroll
  for (int j = 0; j < 8; j++) {
    const int o = j * 16 + fr;
    const float bs = bias[o];
    f32x4 v;
    v.x = 1.f / (1.f + __expf(-(acc[j].x + bs)));
    v.y = 1.f / (1.f + __expf(-(acc[j].y + bs)));
    v.z = 1.f / (1.f + __expf(-(acc[j].z + bs)));
    v.w = 1.f / (1.f + __expf(-(acc[j].w + bs)));
    if (o < 64) {  // r-part -> X0'^T row (2+o)*64+b, times hx
      const float* hxp = hx + ((size_t)b << 16) + (size_t)n * 64 + o;
      u16x4 s;
      s.x = f2bf(v.x * hxp[0 * 64]);
      s.y = f2bf(v.y * hxp[1 * 64]);
      s.z = f2bf(v.z * hxp[2 * 64]);
      s.w = f2bf(v.w * hxp[3 * 64]);
      *(u16x4*)&X0p[(size_t)((2 + o) * 64 + b) * NN + n] = s;
    } else {  // u-part -> uout (d_out scratch)
      float* up = uout + (((size_t)b << 10) + n) * 64 + (o - 64);
      up[0 * 64] = v.x; up[1 * 64] = v.y; up[2 * 64] = v.z; up[3 * 64] = v.w;
    }
  }
}

// gconv2 projection: tanh + GRU blend. uin aliases out (same layout) - no restrict.
__global__ __launch_bounds__(256) void proj2(
    const u16* __restrict__ X0, const u16* __restrict__ X1, const u16* __restrict__ X2,
    const u16* __restrict__ X3, const u16* __restrict__ X4,
    const u16* __restrict__ Wt, const float* __restrict__ bias,
    const float* __restrict__ hx, const float* uin, float* out) {
  __shared__ u16 A[64 * KSTR + 16];
  const int t = threadIdx.x;
  const int n0 = blockIdx.x * 64;
  const int b = blockIdx.y;
  u32* A32 = (u32*)A;
  stage_x(A32, X0, 0, b, n0, t);
  stage_x(A32, X1, 1, b, n0, t);
  stage_x(A32, X2, 2, b, n0, t);
  stage_x(A32, X3, 3, b, n0, t);
  stage_x(A32, X4, 4, b, n0, t);
  zero_pad_rows(A, t);
  __syncthreads();

  const int lane = t & 63;
  const int w = t >> 6;
  const int fr = lane & 15;
  const int ko8 = (lane >> 4) * 8;

  f32x4 acc[4];
#pragma unroll
  for (int j = 0; j < 4; j++) acc[j] = f32x4{0.f, 0.f, 0.f, 0.f};

#pragma unroll 2
  for (int kc = 0; kc < KPAD; kc += 32) {
    s16x8 af = *(const s16x8*)&A[(w * 16 + fr) * KSTR + kc + ko8];
    s16x8 bf[4];
#pragma unroll
    for (int j = 0; j < 4; j++)
      bf[j] = *(const s16x8*)&Wt[(size_t)(j * 16 + fr) * KPAD + kc + ko8];
#pragma unroll
    for (int j = 0; j < 4; j++)
      acc[j] = __builtin_amdgcn_mfma_f32_16x16x32_bf16(af, bf[j], acc[j], 0, 0, 0);
  }

  const int nl0 = (lane >> 4) * 4;
  const int n = n0 + w * 16 + nl0;  // + reg
#pragma unroll
  for (int j = 0; j < 4; j++) {
    const int o = j * 16 + fr;
    const float bs = bias[o];
    const size_t base = (((size_t)b << 10) + n) * 64 + o;  // + reg*64
    float c0 = tanhf(acc[j].x + bs);
    float c1 = tanhf(acc[j].y + bs);
    float c2 = tanhf(acc[j].z + bs);
    float c3 = tanhf(acc[j].w + bs);
    float u0 = uin[base + 0 * 64], u1 = uin[base + 1 * 64];
    float u2 = uin[base + 2 * 64], u3 = uin[base + 3 * 64];
    float h0 = hx[base + 0 * 64], h1 = hx[base + 1 * 64];
    float h2 = hx[base + 2 * 64], h3 = hx[base + 3 * 64];
    out[base + 0 * 64] = u0 * h0 + (1.f - u0) * c0;
    out[base + 1 * 64] = u1 * h1 + (1.f - u1) * c1;
    out[base + 2 * 64] = u2 * h2 + (1.f - u2) * c2;
    out[base + 3 * 64] = u3 * h3 + (1.f - u3) * c3;
  }
}

// ---------------- launch ----------------

extern "C" void kernel_launch(void* const* d_in, const int* in_sizes, int n_in,
                              void* d_out, int out_size, void* d_ws, size_t ws_size,
                              hipStream_t stream) {
  (void)in_sizes; (void)n_in; (void)out_size; (void)ws_size;
  const float* inp = (const float*)d_in[0];
  const float* hx  = (const float*)d_in[1];
  const float* s0  = (const float*)d_in[2];
  const float* s1  = (const float*)d_in[3];
  const float* Wo  = (const float*)d_in[4];
  const float* bo  = (const float*)d_in[5];
  const float* Wu  = (const float*)d_in[6];
  const float* bu  = (const float*)d_in[7];
  float* out = (float*)d_out;

  char* p = (char*)d_ws;
  u16* Sb0 = (u16*)p; p += (size_t)NN * NN * 2;
  u16* Sb1 = (u16*)p; p += (size_t)NN * NN * 2;
  const size_t xbytes = (size_t)NCOLS * NN * 2;
  u16* X0T = (u16*)p; p += xbytes;
  u16* X1T = (u16*)p; p += xbytes;
  u16* X2T = (u16*)p; p += xbytes;
  u16* X3T = (u16*)p; p += xbytes;
  u16* X4T = (u16*)p; p += xbytes;
  u16* X0P = (u16*)p; p += xbytes;
  u16* Wt1 = (u16*)p; p += (size_t)128 * KPAD * 2;
  u16* Wt2 = (u16*)p; p += (size_t)64 * KPAD * 2;
  // total ws use: 4 MB + 6*8.25 MB + ~132 KB

  pack_supports<<<dim3(1024), dim3(256), 0, stream>>>(s0, s1, Sb0, Sb1);
  pack_w<<<dim3(6, 128), dim3(64), 0, stream>>>(Wo, Wt1, 128);
  pack_w<<<dim3(6, 64), dim3(64), 0, stream>>>(Wu, Wt2, 64);
  pack_x0_inputs<<<dim3(64), dim3(256), 0, stream>>>(inp, X0T, X0P);
  pack_x0_hx<<<dim3(16, 64), dim3(256), 0, stream>>>(hx, X0T);
  // gconv1 Chebyshev: X1=S0 X0, X3=S1 X0 ; X2=2 S0 X1 - X0, X4=2 S1 X3 - X0
  cheb_gemm<<<dim3(72, 8, 2), dim3(256), 0, stream>>>(Sb0, Sb1, X0T, X0T, X1T, X3T,
                                                      (const u16*)nullptr, 0);
  cheb_gemm<<<dim3(72, 8, 2), dim3(256), 0, stream>>>(Sb0, Sb1, X1T, X3T, X2T, X4T, X0T, 1);
  proj1<<<dim3(16, 64), dim3(256), 0, stream>>>(X0T, X1T, X2T, X3T, X4T, Wt1, bo, hx, X0P, out);
  // gconv2 Chebyshev on X0' (reuse X1..X4 buffers)
  cheb_gemm<<<dim3(72, 8, 2), dim3(256), 0, stream>>>(Sb0, Sb1, X0P, X0P, X1T, X3T,
                                                      (const u16*)nullptr, 0);
  cheb_gemm<<<dim3(72, 8, 2), dim3(256), 0, stream>>>(Sb0, Sb1, X1T, X3T, X2T, X4T, X0P, 1);
  proj2<<<dim3(16, 64), dim3(256), 0, stream>>>(X0P, X1T, X2T, X3T, X4T, Wt2, bu, hx, out, out);
}